// Round 2
// baseline (364.202 us; speedup 1.0000x reference)
//
#include <hip/hip_runtime.h>

// Problem constants (from reference)
#define BB 8
#define LL 4096
#define DIM 1024
#define HH 16
#define MM 64
#define DH 64

// Flat sizes / output offsets (outputs concatenated, read back as f32)
constexpr long long NZ = (long long)BB * LL * DIM;   // 33554432 (z_enforced / frozen_new)
constexpr long long NG = (long long)BB * LL * HH;    // 524288   (per-head scalars)
constexpr long long O_Z   = 0;
constexpr long long O_CRY = NZ;
constexpr long long O_NEW = NZ + NG;
constexpr long long O_CC  = NZ + 2 * NG;
constexpr long long O_FR  = NZ + 3 * NG;

// ---------------------------------------------------------------------------
// Pre-pass: detect whether `crystallised` is stored as int32 (one int per
// entry, values {0,1}) or as packed uint8 bools. We OR the first NG/4 dwords:
//   - uint8 layout: that covers ALL NG bytes; random bools guarantee some
//     byte above byte0 is set -> OR > 1.
//   - int32 layout: first NG/4 entries are all 0/1 -> OR <= 1.
// Safe to read under both layouts (NG/4 dwords = NG bytes).
// ---------------------------------------------------------------------------
#define DETECT_BLOCKS 64
#define DETECT_DWORDS (NG / 4)          // 131072 dwords

__global__ __launch_bounds__(256) void detect_bool_kernel(
    const unsigned int* __restrict__ buf, unsigned int* __restrict__ partials)
{
    __shared__ unsigned int acc;
    if (threadIdx.x == 0) acc = 0u;
    __syncthreads();
    const int per_block = DETECT_DWORDS / DETECT_BLOCKS;   // 2048
    const long long base = (long long)blockIdx.x * per_block;
    unsigned int v = 0u;
    for (int i = threadIdx.x; i < per_block; i += 256)
        v |= buf[base + i];
    atomicOr(&acc, v);
    __syncthreads();
    if (threadIdx.x == 0) partials[blockIdx.x] = acc;
}

// ---------------------------------------------------------------------------
// Main kernel: one block per (b,l). Thread t owns float4 #t of the 1024-dim
// row; head h = t>>4 is owned by 16 contiguous lanes of one wave.
// ---------------------------------------------------------------------------
__global__ __launch_bounds__(256) void crystal_kernel(
    const float4* __restrict__ zc4,
    const float4* __restrict__ zp4,
    const float*  __restrict__ cb,     // [H][M][DH]
    const float4* __restrict__ fr4,
    const int*    __restrict__ ccount, // [B*L*H] int32
    const void*   __restrict__ cry_raw,
    const unsigned int* __restrict__ partials,
    float* __restrict__ out)
{
    __shared__ float zsh[DIM];

    const int t   = threadIdx.x;
    const int bl  = blockIdx.x;
    const long long base4 = (long long)bl * (DIM / 4);
    const int h   = t >> 4;
    const int sub = t & 15;
    const long long g = (long long)bl * HH + h;

    // crystallised layout mode (uniform across grid)
    unsigned int om = 0u;
    #pragma unroll
    for (int i = 0; i < DETECT_BLOCKS; ++i) om |= partials[i];
    const bool u8mode = om > 1u;

    float4 zc = zc4[base4 + t];
    float4 zp = zp4[base4 + t];
    float4 fr = fr4[base4 + t];

    // Stage z row for the (rare) codebook argmin
    reinterpret_cast<float4*>(zsh)[t] = zc;

    // velocity^2 in f64 (exact f32 diffs, f64 accumulate -> order-independent
    // to ~1e-18, matches any f64 reference at the adversarial tau boundary)
    double s;
    {
        double dx = (double)zc.x - (double)zp.x;
        double dy = (double)zc.y - (double)zp.y;
        double dz = (double)zc.z - (double)zp.z;
        double dw = (double)zc.w - (double)zp.w;
        s = dx * dx + dy * dy + dz * dz + dw * dw;
    }
    s += __shfl_xor(s, 1);
    s += __shfl_xor(s, 2);
    s += __shfl_xor(s, 4);
    s += __shfl_xor(s, 8);

    const bool conv = sqrt(s) < 0.01;   // velocity < TAU_CONVERGE
    const int  cc   = ccount[g];
    const int  ccn  = conv ? cc + 1 : 0;
    const bool cry  = u8mode ? (((const unsigned char*)cry_raw)[g] != 0)
                             : (((const int*)cry_raw)[g] != 0);
    const bool newly   = (ccn >= 2) && !cry;
    const bool crystal = cry || newly;

    __syncthreads();   // zsh visible

    float4 frout = fr;
    if (newly) {
        // argmin over M=64 codes of ||z - cb[h][m]||^2.
        // Lane `sub` evaluates codes 4*sub .. 4*sub+3 (ascending -> first-min tiebreak).
        const float4* zh4 = reinterpret_cast<const float4*>(zsh) + h * (DH / 4);
        const float*  cbh = cb + (long long)h * MM * DH;
        double best = 1e300;
        int bidx = 0;
        #pragma unroll
        for (int mm = 0; mm < 4; ++mm) {
            const int m = 4 * sub + mm;
            const float4* row4 = reinterpret_cast<const float4*>(cbh + m * DH);
            double d2 = 0.0;
            #pragma unroll
            for (int k = 0; k < DH / 4; ++k) {
                float4 zv = zh4[k];
                float4 cv = row4[k];
                double a = (double)zv.x - (double)cv.x;
                double b = (double)zv.y - (double)cv.y;
                double c = (double)zv.z - (double)cv.z;
                double d = (double)zv.w - (double)cv.w;
                d2 += a * a + b * b + c * c + d * d;
            }
            if (d2 < best) { best = d2; bidx = m; }
        }
        // reduce argmin across 16 lanes (tie -> lower index, matching argmin)
        #pragma unroll
        for (int mask = 1; mask <= 8; mask <<= 1) {
            double ob = __shfl_xor(best, mask);
            int    oi = __shfl_xor(bidx, mask);
            if (ob < best || (ob == best && oi < bidx)) { best = ob; bidx = oi; }
        }
        const float* erow = cbh + bidx * DH;
        frout.x = erow[4 * sub + 0];
        frout.y = erow[4 * sub + 1];
        frout.z = erow[4 * sub + 2];
        frout.w = erow[4 * sub + 3];
    }

    float4 zout;
    zout.x = crystal ? frout.x : zc.x;
    zout.y = crystal ? frout.y : zc.y;
    zout.z = crystal ? frout.z : zc.z;
    zout.w = crystal ? frout.w : zc.w;

    reinterpret_cast<float4*>(out + O_Z)[base4 + t]  = zout;
    reinterpret_cast<float4*>(out + O_FR)[base4 + t] = frout;
    if (sub == 0) {
        out[O_CRY + g] = crystal ? 1.0f : 0.0f;
        out[O_NEW + g] = newly   ? 1.0f : 0.0f;
        out[O_CC  + g] = (float)ccn;
    }
}

extern "C" void kernel_launch(void* const* d_in, const int* in_sizes, int n_in,
                              void* d_out, int out_size, void* d_ws, size_t ws_size,
                              hipStream_t stream) {
    const float4* zc4 = (const float4*)d_in[0];
    const float4* zp4 = (const float4*)d_in[1];
    const float*  cb  = (const float*)d_in[2];
    const float4* fr4 = (const float4*)d_in[3];
    const int*    cc  = (const int*)d_in[4];
    const void*   cry = d_in[5];
    float* out = (float*)d_out;
    unsigned int* partials = (unsigned int*)d_ws;   // 64 dwords of scratch

    hipLaunchKernelGGL(detect_bool_kernel, dim3(DETECT_BLOCKS), dim3(256), 0, stream,
                       (const unsigned int*)cry, partials);
    hipLaunchKernelGGL(crystal_kernel, dim3(BB * LL), dim3(256), 0, stream,
                       zc4, zp4, cb, fr4, cc, cry, partials, out);
}